// Round 14
// baseline (64.251 us; speedup 1.0000x reference)
//
#include <hip/hip_runtime.h>
#include <math.h>

#define M_ROWS 1536
#define NC 96
#define KG 16
#define FD 8192
#define NS 8
#define MARGIN 0.3f

#define KSPLIT 32
#define KCH 256            /* k per block */
#define BKS 32             /* k per stage */
#define NST (KCH / BKS)    /* 8 stages */
#define BN 64              /* n cols per block */

typedef short v8s __attribute__((ext_vector_type(8)));   // 8 bf16
typedef float v4f __attribute__((ext_vector_type(4)));

// truncation split: hi = top16(x); lo = top16(x - hi); residual <= 2^-16|x|
__device__ __forceinline__ void split4t(float4 v, ushort4* h, ushort4* l) {
    const unsigned int ux = __float_as_uint(v.x), uy = __float_as_uint(v.y);
    const unsigned int uz = __float_as_uint(v.z), uw = __float_as_uint(v.w);
    *h = make_ushort4((unsigned short)(ux >> 16), (unsigned short)(uy >> 16),
                      (unsigned short)(uz >> 16), (unsigned short)(uw >> 16));
    const float rx = v.x - __uint_as_float(ux & 0xffff0000u);
    const float ry = v.y - __uint_as_float(uy & 0xffff0000u);
    const float rz = v.z - __uint_as_float(uz & 0xffff0000u);
    const float rw = v.w - __uint_as_float(uw & 0xffff0000u);
    *l = make_ushort4((unsigned short)(__float_as_uint(rx) >> 16),
                      (unsigned short)(__float_as_uint(ry) >> 16),
                      (unsigned short)(__float_as_uint(rz) >> 16),
                      (unsigned short)(__float_as_uint(rw) >> 16));
}

// async global->LDS, 16B per lane (dest = wave-uniform base + lane*16)
__device__ __forceinline__ void gload16u(const unsigned short* g, unsigned short* lds) {
    __builtin_amdgcn_global_load_lds(
        (const __attribute__((address_space(1))) void*)g,
        (__attribute__((address_space(3))) void*)lds, 16, 0, 0);
}

// ---------------- K1: centers (+bf16 hi/lo split) + norm partials ----------------
__global__ void centers_kernel(const float* __restrict__ feats,
                               float* __restrict__ centers,
                               unsigned short* __restrict__ ch,   // [96][8192] bf16 hi
                               unsigned short* __restrict__ cl,   // [96][8192] bf16 lo
                               float* __restrict__ fnp,   // [4][1536]
                               float* __restrict__ cnp) { // [4][96]
    const int c = blockIdx.x;
    const int bd = blockIdx.y;
    const int tid = threadIdx.x;

    float sq[KG];
#pragma unroll
    for (int k = 0; k < KG; ++k) sq[k] = 0.f;
    float cp = 0.f;

#pragma unroll
    for (int it = 0; it < 2; ++it) {
        const int base = bd * 2048 + it * 1024 + tid * 4;
        float4 acc = make_float4(0.f, 0.f, 0.f, 0.f);
#pragma unroll
        for (int k = 0; k < KG; ++k) {
            const float4 v = *(const float4*)&feats[(size_t)(c * KG + k) * FD + base];
            acc.x += v.x; acc.y += v.y; acc.z += v.z; acc.w += v.w;
            sq[k] += v.x * v.x + v.y * v.y + v.z * v.z + v.w * v.w;
        }
        float4 cv = make_float4(acc.x * 0.0625f, acc.y * 0.0625f,
                                acc.z * 0.0625f, acc.w * 0.0625f);
        *(float4*)&centers[(size_t)c * FD + base] = cv;
        ushort4 h, l; split4t(cv, &h, &l);
        *(ushort4*)&ch[(size_t)c * FD + base] = h;
        *(ushort4*)&cl[(size_t)c * FD + base] = l;
        cp += cv.x * cv.x + cv.y * cv.y + cv.z * cv.z + cv.w * cv.w;
    }

    const int lane = tid & 63;
    const int w = tid >> 6;
    __shared__ float wred[4][17];
#pragma unroll
    for (int k = 0; k < KG; ++k) {
        float v = sq[k];
#pragma unroll
        for (int off = 32; off > 0; off >>= 1) v += __shfl_down(v, off, 64);
        if (lane == 0) wred[w][k] = v;
    }
    {
        float v = cp;
#pragma unroll
        for (int off = 32; off > 0; off >>= 1) v += __shfl_down(v, off, 64);
        if (lane == 0) wred[w][16] = v;
    }
    __syncthreads();
    if (tid < 17) {
        const float t = wred[0][tid] + wred[1][tid] + wred[2][tid] + wred[3][tid];
        if (tid < 16) fnp[bd * M_ROWS + c * KG + tid] = t;
        else          cnp[bd * NC + c] = t;
    }
}

// ---------------- K2: bf16x3 MFMA partial GEMM ----------------
// 768 blocks = 24 nb x 32 ks (bid%8==ks%8 pins k-slice to one XCD), 4 waves,
// wave = 48m x 32n. R14: A staged via global_load_lds DMA from PRE-SPLIT
// centers (per-lane global addr -> frag-linear LDS; no VALU, no ds_writes).
// B reg-staged + split4t (R11's proven path). Double-buffer, 1 barrier/stage.
__global__ __launch_bounds__(256) void gemm14_kernel(const unsigned short* __restrict__ ch,
                                                     const unsigned short* __restrict__ cl,
                                                     const float* __restrict__ feats,
                                                     float* __restrict__ part) { // [96][32][1536]
    const int bid = blockIdx.x;
    const int ks = bid & 31;
    const int nb = bid >> 5;
    const int tid = threadIdx.x;
    const int j0 = nb * BN;
    const int k0b = ks * KCH;

    // AHL: 12 tiles of 512 bf16 (tile 2m = hi of m-tile m, 2m+1 = lo)
    __shared__ unsigned short AHL[2][12 * 512];             // 12 KB per buf
    __shared__ unsigned short BH[2][4 * 512], BL[2][4 * 512]; // 8 KB per buf

    // A DMA source map: chunk c = tid + i*256 (c<768): tile t=c>>6, lane l=c&63
    const unsigned short* asrc[3];
    int albase[3];
#pragma unroll
    for (int i = 0; i < 3; ++i) {
        const int cchunk = tid + i * 256;
        const int t = cchunk >> 6, l = cchunk & 63;
        const int mt = t >> 1;
        const unsigned short* basep = (t & 1) ? cl : ch;
        asrc[i] = basep + (size_t)(mt * 16 + (l & 15)) * FD + (l >> 4) * 8;
        albase[i] = (i * 256 + (tid & 192)) * 8;   // ushort offset of wave chunk
    }
    // B staging map (R11): element (row n, k) -> tile n>>4, lane (n&15)|((k>>3)<<4)
    int boff[2], bidx[2];
#pragma unroll
    for (int i = 0; i < 2; ++i) {
        const int q = tid + i * 256;                 // B: 64 rows x 32 k / 4
        const int n = q >> 3, kk = (q & 7) * 4;
        boff[i] = (j0 + n) * FD + kk;
        bidx[i] = (n >> 4) * 512 + ((n & 15) | ((kk >> 3) << 4)) * 8 + (kk & 7);
    }

    float4 pb[2];
    // prologue: stage 0 -> buf 0
#pragma unroll
    for (int i = 0; i < 3; ++i) gload16u(asrc[i] + k0b, &AHL[0][albase[i]]);
#pragma unroll
    for (int i = 0; i < 2; ++i) pb[i] = *(const float4*)&feats[boff[i] + k0b];
#pragma unroll
    for (int i = 0; i < 2; ++i) {
        ushort4 h, l; split4t(pb[i], &h, &l);
        *(ushort4*)&BH[0][bidx[i]] = h; *(ushort4*)&BL[0][bidx[i]] = l;
    }
    __syncthreads();

    v4f acc[3][2];
#pragma unroll
    for (int a = 0; a < 3; ++a)
#pragma unroll
        for (int b = 0; b < 2; ++b) {
            acc[a][b][0] = 0.f; acc[a][b][1] = 0.f;
            acc[a][b][2] = 0.f; acc[a][b][3] = 0.f;
        }

    const int w = tid >> 6, lane = tid & 63;
    const int wm = w >> 1, wn = w & 1;      // wave: m-tiles wm*3..+2, n-tiles wn*2..+1
    const int fo = lane * 8;

    int cur = 0;
    for (int st = 0; st < NST; ++st) {
        // next stage: A DMA into other buffer + B global loads (fly under MFMA)
        if (st < NST - 1) {
            const int k0 = k0b + (st + 1) * BKS;
#pragma unroll
            for (int i = 0; i < 3; ++i) gload16u(asrc[i] + k0, &AHL[cur ^ 1][albase[i]]);
#pragma unroll
            for (int i = 0; i < 2; ++i) pb[i] = *(const float4*)&feats[boff[i] + k0];
        }

        // compute: 2 B-frag pairs + 3 A-frag pairs -> 10 ds_read_b128, 18 MFMA
        v8s Bhf[2], Blf[2];
#pragma unroll
        for (int nt = 0; nt < 2; ++nt) {
            Bhf[nt] = *(const v8s*)&BH[cur][(wn * 2 + nt) * 512 + fo];
            Blf[nt] = *(const v8s*)&BL[cur][(wn * 2 + nt) * 512 + fo];
        }
#pragma unroll
        for (int mt = 0; mt < 3; ++mt) {
            const int M = wm * 3 + mt;
            const v8s Ahf = *(const v8s*)&AHL[cur][(2 * M) * 512 + fo];
            const v8s Alf = *(const v8s*)&AHL[cur][(2 * M + 1) * 512 + fo];
#pragma unroll
            for (int nt = 0; nt < 2; ++nt) {
                acc[mt][nt] = __builtin_amdgcn_mfma_f32_16x16x32_bf16(Ahf, Bhf[nt], acc[mt][nt], 0, 0, 0);
                acc[mt][nt] = __builtin_amdgcn_mfma_f32_16x16x32_bf16(Ahf, Blf[nt], acc[mt][nt], 0, 0, 0);
                acc[mt][nt] = __builtin_amdgcn_mfma_f32_16x16x32_bf16(Alf, Bhf[nt], acc[mt][nt], 0, 0, 0);
            }
        }

        // write next stage's B into the other buffer
        if (st < NST - 1) {
            const int d = cur ^ 1;
#pragma unroll
            for (int i = 0; i < 2; ++i) {
                ushort4 h, l; split4t(pb[i], &h, &l);
                *(ushort4*)&BH[d][bidx[i]] = h; *(ushort4*)&BL[d][bidx[i]] = l;
            }
        }
        __syncthreads();   // drains DMA vmcnt + orders B writes
        cur ^= 1;
    }

    // epilogue: C/D layout (m89-verified): col = lane&15, row = (lane>>4)*4 + j
    const int col = lane & 15, r0 = (lane >> 4) * 4;
#pragma unroll
    for (int mt = 0; mt < 3; ++mt) {
#pragma unroll
        for (int nt = 0; nt < 2; ++nt) {
            const int n = j0 + (wn * 2 + nt) * 16 + col;
#pragma unroll
            for (int j = 0; j < 4; ++j) {
                const int m = (wm * 3 + mt) * 16 + r0 + j;
                part[((size_t)m * KSPLIT + ks) * M_ROWS + n] = acc[mt][nt][j];
            }
        }
    }
}

// ---------------- K3: finalize d2 + masked argmax/argmin (512 thr) ----------------
__global__ __launch_bounds__(512) void select_kernel(const float* __restrict__ part,
                                                     const float* __restrict__ fnp,
                                                     const float* __restrict__ cnp,
                                                     const int* __restrict__ labels,
                                                     int* __restrict__ pinds,
                                                     int* __restrict__ ninds) {
    const int c = blockIdx.x;
    const int tid = threadIdx.x;
    const int anchor = labels[c * KG];

    float cn = 0.f;
#pragma unroll
    for (int b = 0; b < 4; ++b) cn += cnp[b * NC + c];

    float bestp = -INFINITY; int bpi = 1 << 30;
    float bestn =  INFINITY; int bni = 1 << 30;

    const float* pc = part + (size_t)c * KSPLIT * M_ROWS;
    for (int j = tid; j < M_ROWS; j += 512) {
        float dot = 0.f;
#pragma unroll
        for (int p = 0; p < KSPLIT; ++p)
            dot += pc[(size_t)p * M_ROWS + j];
        float fn = 0.f;
#pragma unroll
        for (int b = 0; b < 4; ++b) fn += fnp[b * M_ROWS + j];
        const float d2 = cn + fn - 2.f * dot;
        const bool pos = (labels[j] == anchor);
        if (pos) {
            if (d2 > bestp || (d2 == bestp && j < bpi)) { bestp = d2; bpi = j; }
        } else {
            if (d2 < bestn || (d2 == bestn && j < bni)) { bestn = d2; bni = j; }
        }
    }

    __shared__ float sv[512];
    __shared__ int   si[512];
    sv[tid] = bestp; si[tid] = bpi; __syncthreads();
    for (int s = 256; s > 0; s >>= 1) {
        if (tid < s) {
            if (sv[tid + s] > sv[tid] ||
                (sv[tid + s] == sv[tid] && si[tid + s] < si[tid])) {
                sv[tid] = sv[tid + s]; si[tid] = si[tid + s];
            }
        }
        __syncthreads();
    }
    if (tid == 0) pinds[c] = si[0];
    __syncthreads();
    sv[tid] = bestn; si[tid] = bni; __syncthreads();
    for (int s = 256; s > 0; s >>= 1) {
        if (tid < s) {
            if (sv[tid + s] < sv[tid] ||
                (sv[tid + s] == sv[tid] && si[tid + s] < si[tid])) {
                sv[tid] = sv[tid + s]; si[tid] = si[tid + s];
            }
        }
        __syncthreads();
    }
    if (tid == 0) ninds[c] = si[0];
}

// ---------------- K4: local distances + DP + fused loss (last block) ----------------
__global__ void local_kernel(const float* __restrict__ centers,
                             const float* __restrict__ localf,
                             const int* __restrict__ pinds,
                             const int* __restrict__ ninds,
                             float* __restrict__ res,   // [2][96]
                             int* __restrict__ counter,
                             float* __restrict__ out) {
    const int c = blockIdx.x;
    const int which = blockIdx.y;
    const int tid = threadIdx.x;
    const int idx = (which == 0) ? pinds[c] : ninds[c];

    __shared__ float xl[NS * 1028];
    __shared__ float yl[NS * 1032];
    __shared__ float sred[256];
    __shared__ float dmat[64];
    __shared__ float xx[8], yy[8], xyv[64];
    __shared__ int lastFlag;

#pragma unroll
    for (int it = 0; it < 8; ++it) {
        const int q = tid + it * 256;
        const float4 v = *(const float4*)&centers[(size_t)c * FD + q * 4];
        const int i = q >> 8;
        const int d = (q * 4) & 1023;
        *(float4*)&xl[i * 1028 + d] = v;

        const float4 w = *(const float4*)&localf[(size_t)idx * FD + q * 4];
        const int jb = (q * 4) & 7;
        const int dd = q >> 1;
        yl[(jb + 0) * 1032 + dd] = w.x;
        yl[(jb + 1) * 1032 + dd] = w.y;
        yl[(jb + 2) * 1032 + dd] = w.z;
        yl[(jb + 3) * 1032 + dd] = w.w;
    }
    __syncthreads();

    const int p = tid >> 2, c4 = tid & 3;
    const int i = p >> 3, j = p & 7;
    float s = 0.f;
    for (int t = 0; t < 64; ++t) {
        const int d = c4 * 4 + t * 16;
        const float4 xv = *(const float4*)&xl[i * 1028 + d];
        const float4 yv = *(const float4*)&yl[j * 1032 + d];
        s += xv.x * yv.x + xv.y * yv.y + xv.z * yv.z + xv.w * yv.w;
    }
    sred[tid] = s;
    __syncthreads();
    if (tid < 64)
        xyv[tid] = sred[tid * 4] + sred[tid * 4 + 1] + sred[tid * 4 + 2] + sred[tid * 4 + 3];

    float s2 = 0.f;
    if (tid < 64) {
        const int r = tid >> 2;
        const float* base = (r < 8) ? &xl[r * 1028] : &yl[(r - 8) * 1032];
        for (int t = 0; t < 64; ++t) {
            const int d = c4 * 4 + t * 16;
            const float4 v = *(const float4*)&base[d];
            s2 += v.x * v.x + v.y * v.y + v.z * v.z + v.w * v.w;
        }
    }
    __syncthreads();
    sred[tid] = s2;
    __syncthreads();
    if (tid < 16) {
        const float v = sred[tid * 4] + sred[tid * 4 + 1] + sred[tid * 4 + 2] + sred[tid * 4 + 3];
        if (tid < 8) xx[tid] = v; else yy[tid - 8] = v;
    }
    __syncthreads();

    if (tid < 64) {
        const float d2 = xx[i] + yy[j] - 2.f * xyv[tid];
        const float d = sqrtf(fmaxf(d2, 1e-12f));
        dmat[tid] = tanhf(0.5f * d);
    }
    __syncthreads();

    if (tid == 0) {
        float prev[8], cur[8];
        cur[0] = dmat[0];
#pragma unroll
        for (int jj = 1; jj < 8; ++jj) cur[jj] = cur[jj - 1] + dmat[jj];
        for (int ii = 1; ii < 8; ++ii) {
#pragma unroll
            for (int jj = 0; jj < 8; ++jj) prev[jj] = cur[jj];
            cur[0] = prev[0] + dmat[ii * 8];
#pragma unroll
            for (int jj = 1; jj < 8; ++jj)
                cur[jj] = fminf(prev[jj], cur[jj - 1]) + dmat[ii * 8 + jj];
        }
        res[which * NC + c] = cur[7];
        __threadfence();
        const int old = atomicAdd(counter, 1);
        lastFlag = (old == 2 * NC - 1);
    }
    __syncthreads();

    // last finishing block computes the final loss (deterministic fixed-order sum)
    if (lastFlag) {
        __threadfence();
        float v = 0.f;
        if (tid < NC) v = fmaxf(res[tid] - res[NC + tid] + MARGIN, 0.f);
#pragma unroll
        for (int off = 32; off > 0; off >>= 1) v += __shfl_down(v, off, 64);
        __shared__ float w4[4];
        const int lane = tid & 63, wv = tid >> 6;
        if (lane == 0) w4[wv] = v;
        __syncthreads();
        if (tid == 0) out[0] = (w4[0] + w4[1]) * (1.f / NC);
    }
}

extern "C" void kernel_launch(void* const* d_in, const int* in_sizes, int n_in,
                              void* d_out, int out_size, void* d_ws, size_t ws_size,
                              hipStream_t stream) {
    const float* feats  = (const float*)d_in[0];
    const int*   labels = (const int*)d_in[1];
    const float* localf = (const float*)d_in[2];
    float* out = (float*)d_out;

    float* centers = (float*)d_ws;                          // 96*8192 f32
    float* part    = centers + (size_t)NC * FD;             // 96*32*1536 f32
    float* fnp     = part + (size_t)NC * KSPLIT * M_ROWS;   // 4*1536
    float* cnp     = fnp + 4 * M_ROWS;                      // 4*96
    float* res     = cnp + 4 * NC;                          // 2*96
    unsigned short* ch = (unsigned short*)(res + 2 * NC);   // 96*8192 bf16
    unsigned short* cl = ch + (size_t)NC * FD;              // 96*8192 bf16
    int*   pinds   = (int*)(cl + (size_t)NC * FD);          // 96
    int*   ninds   = pinds + NC;                            // 96
    int*   counter = ninds + NC;                            // 1

    hipMemsetAsync(counter, 0, sizeof(int), stream);
    hipLaunchKernelGGL(centers_kernel, dim3(NC, 4), dim3(256), 0, stream,
                       feats, centers, ch, cl, fnp, cnp);
    hipLaunchKernelGGL(gemm14_kernel, dim3(24 * KSPLIT), dim3(256), 0, stream,
                       ch, cl, feats, part);
    hipLaunchKernelGGL(select_kernel, dim3(NC), dim3(512), 0, stream,
                       part, fnp, cnp, labels, pinds, ninds);
    hipLaunchKernelGGL(local_kernel, dim3(NC, 2), dim3(256), 0, stream,
                       centers, localf, pinds, ninds, res, counter, out);
}

// Round 15
// 50.658 us; speedup vs baseline: 1.2683x; 1.2683x over previous
//
#include <hip/hip_runtime.h>
#include <math.h>

#define M_ROWS 1536
#define NC 96
#define KG 16
#define FD 8192
#define NS 8
#define MARGIN 0.3f

#define KSPLIT 32
#define KCH 256            /* k per block */
#define BKS 32             /* k per stage */
#define NST (KCH / BKS)    /* 8 stages */
#define BN 64              /* n cols per block */

typedef short v8s __attribute__((ext_vector_type(8)));   // 8 bf16
typedef float v4f __attribute__((ext_vector_type(4)));

// truncation split: hi = top16(x); lo = top16(x - hi)  (4 ops/float)
// residual <= 2^-16 |x| -> d2 err ~4e-3, selection-safe (gaps O(6)).
__device__ __forceinline__ void split4t(float4 v, ushort4* h, ushort4* l) {
    const unsigned int ux = __float_as_uint(v.x), uy = __float_as_uint(v.y);
    const unsigned int uz = __float_as_uint(v.z), uw = __float_as_uint(v.w);
    *h = make_ushort4((unsigned short)(ux >> 16), (unsigned short)(uy >> 16),
                      (unsigned short)(uz >> 16), (unsigned short)(uw >> 16));
    const float rx = v.x - __uint_as_float(ux & 0xffff0000u);
    const float ry = v.y - __uint_as_float(uy & 0xffff0000u);
    const float rz = v.z - __uint_as_float(uz & 0xffff0000u);
    const float rw = v.w - __uint_as_float(uw & 0xffff0000u);
    *l = make_ushort4((unsigned short)(__float_as_uint(rx) >> 16),
                      (unsigned short)(__float_as_uint(ry) >> 16),
                      (unsigned short)(__float_as_uint(rz) >> 16),
                      (unsigned short)(__float_as_uint(rw) >> 16));
}

// ---------------- K1: centers + squared-norm partials ----------------
__global__ void centers_kernel(const float* __restrict__ feats,
                               float* __restrict__ centers,
                               float* __restrict__ fnp,   // [4][1536]
                               float* __restrict__ cnp) { // [4][96]
    const int c = blockIdx.x;
    const int bd = blockIdx.y;
    const int tid = threadIdx.x;

    float sq[KG];
#pragma unroll
    for (int k = 0; k < KG; ++k) sq[k] = 0.f;
    float cp = 0.f;

#pragma unroll
    for (int it = 0; it < 2; ++it) {
        const int base = bd * 2048 + it * 1024 + tid * 4;
        float4 acc = make_float4(0.f, 0.f, 0.f, 0.f);
#pragma unroll
        for (int k = 0; k < KG; ++k) {
            const float4 v = *(const float4*)&feats[(size_t)(c * KG + k) * FD + base];
            acc.x += v.x; acc.y += v.y; acc.z += v.z; acc.w += v.w;
            sq[k] += v.x * v.x + v.y * v.y + v.z * v.z + v.w * v.w;
        }
        float4 cv = make_float4(acc.x * 0.0625f, acc.y * 0.0625f,
                                acc.z * 0.0625f, acc.w * 0.0625f);
        *(float4*)&centers[(size_t)c * FD + base] = cv;
        cp += cv.x * cv.x + cv.y * cv.y + cv.z * cv.z + cv.w * cv.w;
    }

    const int lane = tid & 63;
    const int w = tid >> 6;
    __shared__ float wred[4][17];
#pragma unroll
    for (int k = 0; k < KG; ++k) {
        float v = sq[k];
#pragma unroll
        for (int off = 32; off > 0; off >>= 1) v += __shfl_down(v, off, 64);
        if (lane == 0) wred[w][k] = v;
    }
    {
        float v = cp;
#pragma unroll
        for (int off = 32; off > 0; off >>= 1) v += __shfl_down(v, off, 64);
        if (lane == 0) wred[w][16] = v;
    }
    __syncthreads();
    if (tid < 17) {
        const float t = wred[0][tid] + wred[1][tid] + wred[2][tid] + wred[3][tid];
        if (tid < 16) fnp[bd * M_ROWS + c * KG + tid] = t;
        else          cnp[bd * NC + c] = t;
    }
}

// ---------------- K2: bf16x3 MFMA partial GEMM (R11-exact) ----------------
// 768 blocks = 24 nb x 32 ks (bid%8==ks%8 pins k-slice to one XCD), 4 waves,
// wave = 48m x 32n (2x2). Convert-once-at-staging (truncation split), frag-
// linear LDS (lane*16B, conflict-free b128), double-buffer, 1 barrier/stage.
__global__ __launch_bounds__(256) void gemm11_kernel(const float* __restrict__ centers,
                                                     const float* __restrict__ feats,
                                                     float* __restrict__ part) { // [96][32][1536]
    const int bid = blockIdx.x;
    const int ks = bid & 31;
    const int nb = bid >> 5;
    const int tid = threadIdx.x;
    const int j0 = nb * BN;
    const int k0b = ks * KCH;

    __shared__ unsigned short AH[2][6 * 512], AL[2][6 * 512];   // 6 m-tiles
    __shared__ unsigned short BH[2][4 * 512], BL[2][4 * 512];   // 4 n-tiles

    // staging maps: element (row r, k) -> tile r>>4, lane (r&15)|((k>>3)<<4),
    // elem k&7. A thread's 4 consecutive k share (k>>3) -> one ushort4 write.
    int aoff[3], aidx[3];
#pragma unroll
    for (int i = 0; i < 3; ++i) {
        const int q = tid + i * 256;                 // A: 96 rows x 32 k / 4
        const int m = q >> 3, kk = (q & 7) * 4;
        aoff[i] = m * FD + kk;
        aidx[i] = (m >> 4) * 512 + ((m & 15) | ((kk >> 3) << 4)) * 8 + (kk & 7);
    }
    int boff[2], bidx[2];
#pragma unroll
    for (int i = 0; i < 2; ++i) {
        const int q = tid + i * 256;                 // B: 64 rows x 32 k / 4
        const int n = q >> 3, kk = (q & 7) * 4;
        boff[i] = (j0 + n) * FD + kk;
        bidx[i] = (n >> 4) * 512 + ((n & 15) | ((kk >> 3) << 4)) * 8 + (kk & 7);
    }

    float4 pa[3], pb[2];
    // prologue: stage 0 -> buf 0
#pragma unroll
    for (int i = 0; i < 3; ++i) pa[i] = *(const float4*)&centers[aoff[i] + k0b];
#pragma unroll
    for (int i = 0; i < 2; ++i) pb[i] = *(const float4*)&feats[boff[i] + k0b];
#pragma unroll
    for (int i = 0; i < 3; ++i) {
        ushort4 h, l; split4t(pa[i], &h, &l);
        *(ushort4*)&AH[0][aidx[i]] = h; *(ushort4*)&AL[0][aidx[i]] = l;
    }
#pragma unroll
    for (int i = 0; i < 2; ++i) {
        ushort4 h, l; split4t(pb[i], &h, &l);
        *(ushort4*)&BH[0][bidx[i]] = h; *(ushort4*)&BL[0][bidx[i]] = l;
    }
    __syncthreads();

    v4f acc[3][2];
#pragma unroll
    for (int a = 0; a < 3; ++a)
#pragma unroll
        for (int b = 0; b < 2; ++b) {
            acc[a][b][0] = 0.f; acc[a][b][1] = 0.f;
            acc[a][b][2] = 0.f; acc[a][b][3] = 0.f;
        }

    const int w = tid >> 6, lane = tid & 63;
    const int wm = w >> 1, wn = w & 1;      // wave: m-tiles wm*3..+2, n-tiles wn*2..+1
    const int fo = lane * 8;

    int cur = 0;
    for (int st = 0; st < NST; ++st) {
        // issue next stage's global loads; latency hides under MFMA below
        if (st < NST - 1) {
            const int k0 = k0b + (st + 1) * BKS;
#pragma unroll
            for (int i = 0; i < 3; ++i) pa[i] = *(const float4*)&centers[aoff[i] + k0];
#pragma unroll
            for (int i = 0; i < 2; ++i) pb[i] = *(const float4*)&feats[boff[i] + k0];
        }

        // compute: 2 B-frag pairs + 3 A-frag pairs -> 10 ds_read_b128, 18 MFMA
        v8s Bhf[2], Blf[2];
#pragma unroll
        for (int nt = 0; nt < 2; ++nt) {
            Bhf[nt] = *(const v8s*)&BH[cur][(wn * 2 + nt) * 512 + fo];
            Blf[nt] = *(const v8s*)&BL[cur][(wn * 2 + nt) * 512 + fo];
        }
#pragma unroll
        for (int mt = 0; mt < 3; ++mt) {
            const v8s Ahf = *(const v8s*)&AH[cur][(wm * 3 + mt) * 512 + fo];
            const v8s Alf = *(const v8s*)&AL[cur][(wm * 3 + mt) * 512 + fo];
#pragma unroll
            for (int nt = 0; nt < 2; ++nt) {
                acc[mt][nt] = __builtin_amdgcn_mfma_f32_16x16x32_bf16(Ahf, Bhf[nt], acc[mt][nt], 0, 0, 0);
                acc[mt][nt] = __builtin_amdgcn_mfma_f32_16x16x32_bf16(Ahf, Blf[nt], acc[mt][nt], 0, 0, 0);
                acc[mt][nt] = __builtin_amdgcn_mfma_f32_16x16x32_bf16(Alf, Bhf[nt], acc[mt][nt], 0, 0, 0);
            }
        }

        // convert + write next stage into the other buffer
        if (st < NST - 1) {
            const int d = cur ^ 1;
#pragma unroll
            for (int i = 0; i < 3; ++i) {
                ushort4 h, l; split4t(pa[i], &h, &l);
                *(ushort4*)&AH[d][aidx[i]] = h; *(ushort4*)&AL[d][aidx[i]] = l;
            }
#pragma unroll
            for (int i = 0; i < 2; ++i) {
                ushort4 h, l; split4t(pb[i], &h, &l);
                *(ushort4*)&BH[d][bidx[i]] = h; *(ushort4*)&BL[d][bidx[i]] = l;
            }
        }
        __syncthreads();
        cur ^= 1;
    }

    // epilogue: C/D layout (m89-verified): col = lane&15, row = (lane>>4)*4 + j
    const int col = lane & 15, r0 = (lane >> 4) * 4;
#pragma unroll
    for (int mt = 0; mt < 3; ++mt) {
#pragma unroll
        for (int nt = 0; nt < 2; ++nt) {
            const int n = j0 + (wn * 2 + nt) * 16 + col;
#pragma unroll
            for (int j = 0; j < 4; ++j) {
                const int m = (wm * 3 + mt) * 16 + r0 + j;
                part[((size_t)m * KSPLIT + ks) * M_ROWS + n] = acc[mt][nt][j];
            }
        }
    }
}

// ---------------- K3: finalize d2 + masked argmax/argmin (512 thr) ----------------
// 96 blocks = 0.37/CU; latency-bound on 32 strided partial reads. 512 threads
// doubles per-block MLP (the only isolated untested change from R13/R14).
__global__ __launch_bounds__(512) void select_kernel(const float* __restrict__ part,
                                                     const float* __restrict__ fnp,
                                                     const float* __restrict__ cnp,
                                                     const int* __restrict__ labels,
                                                     int* __restrict__ pinds,
                                                     int* __restrict__ ninds) {
    const int c = blockIdx.x;
    const int tid = threadIdx.x;
    const int anchor = labels[c * KG];

    float cn = 0.f;
#pragma unroll
    for (int b = 0; b < 4; ++b) cn += cnp[b * NC + c];

    float bestp = -INFINITY; int bpi = 1 << 30;
    float bestn =  INFINITY; int bni = 1 << 30;

    const float* pc = part + (size_t)c * KSPLIT * M_ROWS;
    for (int j = tid; j < M_ROWS; j += 512) {
        float dot = 0.f;
#pragma unroll
        for (int p = 0; p < KSPLIT; ++p)
            dot += pc[(size_t)p * M_ROWS + j];
        float fn = 0.f;
#pragma unroll
        for (int b = 0; b < 4; ++b) fn += fnp[b * M_ROWS + j];
        const float d2 = cn + fn - 2.f * dot;
        const bool pos = (labels[j] == anchor);
        if (pos) {
            if (d2 > bestp || (d2 == bestp && j < bpi)) { bestp = d2; bpi = j; }
        } else {
            if (d2 < bestn || (d2 == bestn && j < bni)) { bestn = d2; bni = j; }
        }
    }

    __shared__ float sv[512];
    __shared__ int   si[512];
    sv[tid] = bestp; si[tid] = bpi; __syncthreads();
    for (int s = 256; s > 0; s >>= 1) {
        if (tid < s) {
            if (sv[tid + s] > sv[tid] ||
                (sv[tid + s] == sv[tid] && si[tid + s] < si[tid])) {
                sv[tid] = sv[tid + s]; si[tid] = si[tid + s];
            }
        }
        __syncthreads();
    }
    if (tid == 0) pinds[c] = si[0];
    __syncthreads();
    sv[tid] = bestn; si[tid] = bni; __syncthreads();
    for (int s = 256; s > 0; s >>= 1) {
        if (tid < s) {
            if (sv[tid + s] < sv[tid] ||
                (sv[tid + s] == sv[tid] && si[tid + s] < si[tid])) {
                sv[tid] = sv[tid + s]; si[tid] = si[tid + s];
            }
        }
        __syncthreads();
    }
    if (tid == 0) ninds[c] = si[0];
}

// ---------------- K4: local stripe distances + DP ----------------
__global__ void local_kernel(const float* __restrict__ centers,
                             const float* __restrict__ localf,
                             const int* __restrict__ pinds,
                             const int* __restrict__ ninds,
                             float* __restrict__ res) { // [2][96]
    const int c = blockIdx.x;
    const int which = blockIdx.y;
    const int tid = threadIdx.x;
    const int idx = (which == 0) ? pinds[c] : ninds[c];

    __shared__ float xl[NS * 1028];
    __shared__ float yl[NS * 1032];
    __shared__ float sred[256];
    __shared__ float dmat[64];
    __shared__ float xx[8], yy[8], xyv[64];

#pragma unroll
    for (int it = 0; it < 8; ++it) {
        const int q = tid + it * 256;
        const float4 v = *(const float4*)&centers[(size_t)c * FD + q * 4];
        const int i = q >> 8;
        const int d = (q * 4) & 1023;
        *(float4*)&xl[i * 1028 + d] = v;

        const float4 w = *(const float4*)&localf[(size_t)idx * FD + q * 4];
        const int jb = (q * 4) & 7;
        const int dd = q >> 1;
        yl[(jb + 0) * 1032 + dd] = w.x;
        yl[(jb + 1) * 1032 + dd] = w.y;
        yl[(jb + 2) * 1032 + dd] = w.z;
        yl[(jb + 3) * 1032 + dd] = w.w;
    }
    __syncthreads();

    const int p = tid >> 2, c4 = tid & 3;
    const int i = p >> 3, j = p & 7;
    float s = 0.f;
    for (int t = 0; t < 64; ++t) {
        const int d = c4 * 4 + t * 16;
        const float4 xv = *(const float4*)&xl[i * 1028 + d];
        const float4 yv = *(const float4*)&yl[j * 1032 + d];
        s += xv.x * yv.x + xv.y * yv.y + xv.z * yv.z + xv.w * yv.w;
    }
    sred[tid] = s;
    __syncthreads();
    if (tid < 64)
        xyv[tid] = sred[tid * 4] + sred[tid * 4 + 1] + sred[tid * 4 + 2] + sred[tid * 4 + 3];

    float s2 = 0.f;
    if (tid < 64) {
        const int r = tid >> 2;
        const float* base = (r < 8) ? &xl[r * 1028] : &yl[(r - 8) * 1032];
        for (int t = 0; t < 64; ++t) {
            const int d = c4 * 4 + t * 16;
            const float4 v = *(const float4*)&base[d];
            s2 += v.x * v.x + v.y * v.y + v.z * v.z + v.w * v.w;
        }
    }
    __syncthreads();
    sred[tid] = s2;
    __syncthreads();
    if (tid < 16) {
        const float v = sred[tid * 4] + sred[tid * 4 + 1] + sred[tid * 4 + 2] + sred[tid * 4 + 3];
        if (tid < 8) xx[tid] = v; else yy[tid - 8] = v;
    }
    __syncthreads();

    if (tid < 64) {
        const float d2 = xx[i] + yy[j] - 2.f * xyv[tid];
        const float d = sqrtf(fmaxf(d2, 1e-12f));
        dmat[tid] = tanhf(0.5f * d);
    }
    __syncthreads();

    if (tid == 0) {
        float prev[8], cur[8];
        cur[0] = dmat[0];
#pragma unroll
        for (int jj = 1; jj < 8; ++jj) cur[jj] = cur[jj - 1] + dmat[jj];
        for (int ii = 1; ii < 8; ++ii) {
#pragma unroll
            for (int jj = 0; jj < 8; ++jj) prev[jj] = cur[jj];
            cur[0] = prev[0] + dmat[ii * 8];
#pragma unroll
            for (int jj = 1; jj < 8; ++jj)
                cur[jj] = fminf(prev[jj], cur[jj - 1]) + dmat[ii * 8 + jj];
        }
        res[which * NC + c] = cur[7];
    }
}

// ---------------- K5: mean(relu(ap - an + margin)) ----------------
__global__ void loss_kernel(const float* __restrict__ res, float* __restrict__ out) {
    const int tid = threadIdx.x; // 128
    float v = 0.f;
    if (tid < NC) v = fmaxf(res[tid] - res[NC + tid] + MARGIN, 0.f);
#pragma unroll
    for (int off = 32; off > 0; off >>= 1) v += __shfl_down(v, off, 64);
    __shared__ float w2[2];
    const int lane = tid & 63, w = tid >> 6;
    if (lane == 0) w2[w] = v;
    __syncthreads();
    if (tid == 0) out[0] = (w2[0] + w2[1]) * (1.f / NC);
}

extern "C" void kernel_launch(void* const* d_in, const int* in_sizes, int n_in,
                              void* d_out, int out_size, void* d_ws, size_t ws_size,
                              hipStream_t stream) {
    const float* feats  = (const float*)d_in[0];
    const int*   labels = (const int*)d_in[1];
    const float* localf = (const float*)d_in[2];
    float* out = (float*)d_out;

    float* centers = (float*)d_ws;                          // 96*8192
    float* part    = centers + (size_t)NC * FD;             // 96*32*1536
    float* fnp     = part + (size_t)NC * KSPLIT * M_ROWS;   // 4*1536
    float* cnp     = fnp + 4 * M_ROWS;                      // 4*96
    float* res     = cnp + 4 * NC;                          // 2*96
    int*   pinds   = (int*)(res + 2 * NC);                  // 96
    int*   ninds   = pinds + NC;                            // 96

    hipLaunchKernelGGL(centers_kernel, dim3(NC, 4), dim3(256), 0, stream,
                       feats, centers, fnp, cnp);
    hipLaunchKernelGGL(gemm11_kernel, dim3(24 * KSPLIT), dim3(256), 0, stream,
                       centers, feats, part);
    hipLaunchKernelGGL(select_kernel, dim3(NC), dim3(512), 0, stream,
                       part, fnp, cnp, labels, pinds, ninds);
    hipLaunchKernelGGL(local_kernel, dim3(NC, 2), dim3(256), 0, stream,
                       centers, localf, pinds, ninds, res);
    hipLaunchKernelGGL(loss_kernel, dim3(1), dim3(128), 0, stream, res, out);
}